// Round 1
// baseline (23320.419 us; speedup 1.0000x reference)
//
#include <hip/hip_runtime.h>
#include <hip/hip_bf16.h>

// GRU model: emb gather -> gi = enc@W_ih+b_ih (fp16 MFMA GEMM)
//            -> 512-step recurrence (persistent kernel, flag barrier/step)
//            -> decode head.
// H=1024, SEQ=512, BATCH=64, VOCAB=32000. Output: [64,2] fp32.

typedef _Float16 half8 __attribute__((ext_vector_type(8)));
typedef float floatx4 __attribute__((ext_vector_type(4)));

#define H 1024
#define SEQ 512
#define BATCH 64
#define NG 3072  // 3*H

// ---------------- workspace layout (bytes) ----------------
// gi16   : SEQ*BATCH*NG fp16                = 201326592
// wihT   : NG*H fp16 (W_ih transposed)      =   6291456
// whhT   : NG*H fp16 (W_hh transposed)      =   6291456
// h16    : 2 * BATCH*H fp16 (ping-pong)     =    262144
// h32    : BATCH*H fp32 (final h only)      =    262144
// cnt    : SEQ ints (step barrier counters) =      2048
static constexpr size_t OFF_GI   = 0;
static constexpr size_t OFF_WIHT = OFF_GI + (size_t)SEQ * BATCH * NG * 2;
static constexpr size_t OFF_WHHT = OFF_WIHT + (size_t)NG * H * 2;
static constexpr size_t OFF_H16  = OFF_WHHT + (size_t)NG * H * 2;
static constexpr size_t OFF_H32  = OFF_H16 + (size_t)2 * BATCH * H * 2;
static constexpr size_t OFF_CNT  = OFF_H32 + (size_t)BATCH * H * 4;

// ---------------- prep: transpose+convert W (fp32 [H][3H] -> fp16 [3H][H]) --
__global__ __launch_bounds__(256) void transpose_w(
    const float* __restrict__ Wih, const float* __restrict__ Whh,
    _Float16* __restrict__ wihT, _Float16* __restrict__ whhT) {
  __shared__ float tile[32][33];
  const float* src = blockIdx.z ? Whh : Wih;
  _Float16* dst = blockIdx.z ? whhT : wihT;
  const int n0 = blockIdx.x * 32, k0 = blockIdx.y * 32;
  const int tx = threadIdx.x & 31, ty = threadIdx.x >> 5;  // ty in [0,8)
  for (int r = 0; r < 4; ++r)
    tile[r * 8 + ty][tx] = src[(size_t)(k0 + r * 8 + ty) * NG + n0 + tx];
  __syncthreads();
  for (int r = 0; r < 4; ++r)
    dst[(size_t)(n0 + r * 8 + ty) * H + k0 + tx] = (_Float16)tile[tx][r * 8 + ty];
}

// ---------------- phase A: gi16[m][c] = emb[ids[m]] @ W_ih + b_ih ----------
// 128x128 tile per WG, 4 waves each 64x64, mfma 16x16x32 f16.
__global__ __launch_bounds__(256) void gemm_gi(
    const int* __restrict__ ids, const float* __restrict__ emb,
    const _Float16* __restrict__ wihT, const float* __restrict__ bih,
    _Float16* __restrict__ gi16) {
  __shared__ _Float16 As[128 * 40];  // [row_m][k], stride 40 (pad: 16B-align + bank-spread)
  __shared__ _Float16 Bs[128 * 40];  // [row_n][k]
  __shared__ int sids[128];
  const int tid = threadIdx.x;
  const int m0 = blockIdx.y * 128, n0 = blockIdx.x * 128;
  if (tid < 128) sids[tid] = ids[m0 + tid];
  const int wave = tid >> 6, lane = tid & 63, quad = lane >> 4, l15 = lane & 15;
  const int wm = wave >> 1, wn = wave & 1;

  floatx4 acc[4][4];
  for (int a = 0; a < 4; ++a)
    for (int b = 0; b < 4; ++b) acc[a][b] = (floatx4){0.f, 0.f, 0.f, 0.f};

  for (int kc = 0; kc < 32; ++kc) {
    __syncthreads();
    {  // stage A: 128 rows x 32 k (gather + fp32->fp16)
      const int row = tid >> 1, kh = tid & 1;
      const float4* s4 =
          (const float4*)(emb + (size_t)sids[row] * H + kc * 32 + kh * 16);
      float4 f0 = s4[0], f1 = s4[1], f2 = s4[2], f3 = s4[3];
      half8 p0 = {(_Float16)f0.x, (_Float16)f0.y, (_Float16)f0.z, (_Float16)f0.w,
                  (_Float16)f1.x, (_Float16)f1.y, (_Float16)f1.z, (_Float16)f1.w};
      half8 p1 = {(_Float16)f2.x, (_Float16)f2.y, (_Float16)f2.z, (_Float16)f2.w,
                  (_Float16)f3.x, (_Float16)f3.y, (_Float16)f3.z, (_Float16)f3.w};
      *(half8*)&As[row * 40 + kh * 16] = p0;
      *(half8*)&As[row * 40 + kh * 16 + 8] = p1;
    }
    for (int i = tid; i < 512; i += 256) {  // stage B: 128 n-rows x 32 k
      const int row = i >> 2, ko = (i & 3) * 8;
      *(half8*)&Bs[row * 40 + ko] =
          *(const half8*)(wihT + (size_t)(n0 + row) * H + kc * 32 + ko);
    }
    __syncthreads();
    half8 a[4], b[4];
    for (int tm = 0; tm < 4; ++tm)
      a[tm] = *(half8*)&As[(wm * 64 + tm * 16 + l15) * 40 + quad * 8];
    for (int tn = 0; tn < 4; ++tn)
      b[tn] = *(half8*)&Bs[(wn * 64 + tn * 16 + l15) * 40 + quad * 8];
    for (int tm = 0; tm < 4; ++tm)
      for (int tn = 0; tn < 4; ++tn)
        acc[tm][tn] =
            __builtin_amdgcn_mfma_f32_16x16x32_f16(a[tm], b[tn], acc[tm][tn], 0, 0, 0);
  }
  // epilogue: + b_ih, store fp16.  D layout: row=quad*4+i, col=l15.
  float bi[4];
  for (int tn = 0; tn < 4; ++tn) bi[tn] = bih[n0 + wn * 64 + tn * 16 + l15];
  for (int tm = 0; tm < 4; ++tm)
    for (int i = 0; i < 4; ++i) {
      const int m = m0 + wm * 64 + tm * 16 + quad * 4 + i;
      _Float16* dst = gi16 + (size_t)m * NG + n0 + wn * 64 + l15;
      for (int tn = 0; tn < 4; ++tn)
        dst[tn * 16] = (_Float16)(acc[tm][tn][i] + bi[tn]);
    }
}

// ---------------- phase B: 512-step recurrence, 256 persistent WGs ---------
// WG w owns j in [4w, 4w+4). LDS holds W_hh cols {r,z,n}x4 (12) + 4 zero cols
// => one 16-wide MFMA N-tile per k-chunk. h fp16 ping-pong in global; own
// h_prev kept in registers; gi(t+1) prefetched before the barrier.
__global__ __launch_bounds__(256) void gru_seq(
    const _Float16* __restrict__ whhT, const _Float16* __restrict__ gi16,
    const float* __restrict__ bhh, _Float16* __restrict__ h16,
    float* __restrict__ h32, int* __restrict__ cnt) {
  __shared__ _Float16 Ws[16 * 1032];  // [col16][k1024 pad8]
  const int tid = threadIdx.x;
  const int j0 = blockIdx.x * 4;
  const int wave = tid >> 6, lane = tid & 63, quad = lane >> 4, l15 = lane & 15;
  const int vbase = wave * 16;

  for (int i = tid; i < 16 * 128; i += 256) {  // W slice -> LDS (cols 12..15 zero)
    const int cl = i >> 7, kb = (i & 127) * 8;
    half8 v = {(_Float16)0, (_Float16)0, (_Float16)0, (_Float16)0,
               (_Float16)0, (_Float16)0, (_Float16)0, (_Float16)0};
    if (cl < 12) {
      const int g = cl >> 2, jj = cl & 3;
      v = *(const half8*)(whhT + (size_t)(g * H + j0 + jj) * H + kb);
    }
    *(half8*)&Ws[cl * 1032 + kb] = v;
  }
  const int jj = l15 & 3, j = j0 + jj;
  const float bh0 = bhh[j], bh1 = bhh[H + j], bh2 = bhh[2 * H + j];
  const int brow = vbase + l15;
  float hprev[4] = {0.f, 0.f, 0.f, 0.f};
  float g0p[4], g1p[4], g2p[4];
  for (int i = 0; i < 4; ++i) {  // prefetch gi for t=0
    const _Float16* gp = gi16 + (size_t)(vbase + quad * 4 + i) * NG + j;
    g0p[i] = (float)gp[0]; g1p[i] = (float)gp[H]; g2p[i] = (float)gp[2 * H];
  }
  __syncthreads();

  for (int t = 0; t < SEQ; ++t) {
    const _Float16* hc = h16 + (t & 1) * (BATCH * H);
    _Float16* hn = h16 + ((t + 1) & 1) * (BATCH * H);
    floatx4 acc0 = {0.f, 0.f, 0.f, 0.f}, acc1 = {0.f, 0.f, 0.f, 0.f};
    const half8* ap = (const half8*)(hc + brow * H);
#pragma unroll
    for (int kc = 0; kc < 32; kc += 2) {
      half8 a0 = ap[kc * 4 + quad];
      half8 b0 = *(const half8*)&Ws[l15 * 1032 + kc * 32 + quad * 8];
      acc0 = __builtin_amdgcn_mfma_f32_16x16x32_f16(a0, b0, acc0, 0, 0, 0);
      half8 a1 = ap[(kc + 1) * 4 + quad];
      half8 b1 = *(const half8*)&Ws[l15 * 1032 + (kc + 1) * 32 + quad * 8];
      acc1 = __builtin_amdgcn_mfma_f32_16x16x32_f16(a1, b1, acc1, 0, 0, 0);
    }
    const floatx4 acc = acc0 + acc1;
    float rp[4], zp[4], np[4];
    for (int i = 0; i < 4; ++i) {  // gates land in lanes l15=0..3(r),4..7(z),8..11(n)
      rp[i] = acc[i];
      zp[i] = __shfl(acc[i], (lane + 4) & 63, 64);
      np[i] = __shfl(acc[i], (lane + 8) & 63, 64);
    }
    float gc0[4], gc1[4], gc2[4];
    for (int i = 0; i < 4; ++i) { gc0[i] = g0p[i]; gc1[i] = g1p[i]; gc2[i] = g2p[i]; }
    const int tn = (t + 1 < SEQ) ? t + 1 : t;  // prefetch next step's gi (step-invariant data)
    for (int i = 0; i < 4; ++i) {
      const _Float16* gp = gi16 + (size_t)(tn * BATCH + vbase + quad * 4 + i) * NG + j;
      g0p[i] = (float)gp[0]; g1p[i] = (float)gp[H]; g2p[i] = (float)gp[2 * H];
    }
    if (l15 < 4) {
      for (int i = 0; i < 4; ++i) {
        const int b = vbase + quad * 4 + i;
        const float r = 1.f / (1.f + __expf(-(gc0[i] + bh0 + rp[i])));
        const float z = 1.f / (1.f + __expf(-(gc1[i] + bh1 + zp[i])));
        const float pre = gc2[i] + r * (np[i] + bh2);
        const float e = __expf(2.f * pre);
        const float n = 1.f - 2.f / (e + 1.f);
        const float hv = (1.f - z) * n + z * hprev[i];
        hprev[i] = hv;
        hn[b * H + j] = (_Float16)hv;
        if (t == SEQ - 1) h32[b * H + j] = hv;
      }
    }
    if (t < SEQ - 1) {  // one device-scope barrier per step
      __threadfence();
      __syncthreads();
      if (tid == 0) {
        atomicAdd(&cnt[t], 1);
        while (__hip_atomic_load(&cnt[t], __ATOMIC_RELAXED,
                                 __HIP_MEMORY_SCOPE_AGENT) < 256) {
          __builtin_amdgcn_s_sleep(8);
        }
      }
      __syncthreads();
      __threadfence();
    }
  }
}

// ---------------- decode head: relu(h@W_dec+b_dec)@W_fc + b_fc ------------
__global__ __launch_bounds__(128) void decode_out(
    const float* __restrict__ h32, const float* __restrict__ Wdec,
    const float* __restrict__ bdec, const float* __restrict__ Wfc,
    const float* __restrict__ bfc, float* __restrict__ out) {
  __shared__ float dec[100];
  const int b = blockIdx.x, t = threadIdx.x;
  const float* h = h32 + b * H;
  if (t < 100) {
    float a = bdec[t];
    for (int k = 0; k < H; ++k) a += h[k] * Wdec[k * 100 + t];
    dec[t] = a > 0.f ? a : 0.f;
  }
  __syncthreads();
  if (t < 2) {
    float o = bfc[t];
    for (int d = 0; d < 100; ++d) o += dec[d] * Wfc[d * 2 + t];
    out[b * 2 + t] = o;
  }
}

// ---------------- launch ---------------------------------------------------
extern "C" void kernel_launch(void* const* d_in, const int* in_sizes, int n_in,
                              void* d_out, int out_size, void* d_ws, size_t ws_size,
                              hipStream_t stream) {
  const int* ids = (const int*)d_in[0];
  const float* emb = (const float*)d_in[1];
  const float* Wih = (const float*)d_in[2];
  const float* Whh = (const float*)d_in[3];
  const float* bih = (const float*)d_in[4];
  const float* bhh = (const float*)d_in[5];
  const float* Wdec = (const float*)d_in[6];
  const float* bdec = (const float*)d_in[7];
  const float* Wfc = (const float*)d_in[8];
  const float* bfc = (const float*)d_in[9];
  float* out = (float*)d_out;

  char* ws = (char*)d_ws;
  _Float16* gi16 = (_Float16*)(ws + OFF_GI);
  _Float16* wihT = (_Float16*)(ws + OFF_WIHT);
  _Float16* whhT = (_Float16*)(ws + OFF_WHHT);
  _Float16* h16 = (_Float16*)(ws + OFF_H16);
  float* h32 = (float*)(ws + OFF_H32);
  int* cnt = (int*)(ws + OFF_CNT);

  // zero-init: h ping buffer 0 (h0 = 0) and step counters (ws is poisoned 0xAA)
  hipMemsetAsync(h16, 0, (size_t)BATCH * H * 2, stream);
  hipMemsetAsync(cnt, 0, (size_t)SEQ * 4, stream);

  transpose_w<<<dim3(NG / 32, H / 32, 2), 256, 0, stream>>>(Wih, Whh, wihT, whhT);
  gemm_gi<<<dim3(NG / 128, (SEQ * BATCH) / 128), 256, 0, stream>>>(ids, emb, wihT,
                                                                   bih, gi16);
  gru_seq<<<256, 256, 0, stream>>>(whhT, gi16, bhh, h16, h32, cnt);
  decode_out<<<BATCH, 128, 0, stream>>>(h32, Wdec, bdec, Wfc, bfc, out);
}

// Round 2
// 11492.146 us; speedup vs baseline: 2.0292x; 2.0292x over previous
//
#include <hip/hip_runtime.h>
#include <hip/hip_bf16.h>

// GRU model: emb gather -> gi = enc@W_ih+b_ih (fp16 MFMA GEMM)
//            -> 512-step recurrence (64 persistent WGs, all-to-all flag barrier)
//            -> decode head.
// H=1024, SEQ=512, BATCH=64, VOCAB=32000. Output: [64,2] fp32.

typedef _Float16 half8 __attribute__((ext_vector_type(8)));
typedef float floatx4 __attribute__((ext_vector_type(4)));

#define H 1024
#define SEQ 512
#define BATCH 64
#define NG 3072  // 3*H

// ---------------- workspace layout (bytes) ----------------
static constexpr size_t OFF_GI   = 0;                                   // SEQ*BATCH*NG fp16
static constexpr size_t OFF_WIHT = OFF_GI + (size_t)SEQ * BATCH * NG * 2;
static constexpr size_t OFF_WHHT = OFF_WIHT + (size_t)NG * H * 2;
static constexpr size_t OFF_H16  = OFF_WHHT + (size_t)NG * H * 2;       // 2 x BATCH*H fp16 ping-pong
static constexpr size_t OFF_H32  = OFF_H16 + (size_t)2 * BATCH * H * 2; // BATCH*H fp32
static constexpr size_t OFF_ARR  = OFF_H32 + (size_t)BATCH * H * 4;     // SEQ*64 arrival bytes

// ---------------- prep: transpose+convert W (fp32 [H][3H] -> fp16 [3H][H]) --
__global__ __launch_bounds__(256) void transpose_w(
    const float* __restrict__ Wih, const float* __restrict__ Whh,
    _Float16* __restrict__ wihT, _Float16* __restrict__ whhT) {
  __shared__ float tile[32][33];
  const float* src = blockIdx.z ? Whh : Wih;
  _Float16* dst = blockIdx.z ? whhT : wihT;
  const int n0 = blockIdx.x * 32, k0 = blockIdx.y * 32;
  const int tx = threadIdx.x & 31, ty = threadIdx.x >> 5;  // ty in [0,8)
  for (int r = 0; r < 4; ++r)
    tile[r * 8 + ty][tx] = src[(size_t)(k0 + r * 8 + ty) * NG + n0 + tx];
  __syncthreads();
  for (int r = 0; r < 4; ++r)
    dst[(size_t)(n0 + r * 8 + ty) * H + k0 + tx] = (_Float16)tile[tx][r * 8 + ty];
}

// ---------------- phase A: gi16[m][c] = emb[ids[m]] @ W_ih + b_ih ----------
// 128x128 tile per WG, 4 waves each 64x64, mfma 16x16x32 f16.
__global__ __launch_bounds__(256) void gemm_gi(
    const int* __restrict__ ids, const float* __restrict__ emb,
    const _Float16* __restrict__ wihT, const float* __restrict__ bih,
    _Float16* __restrict__ gi16) {
  __shared__ _Float16 As[128 * 40];
  __shared__ _Float16 Bs[128 * 40];
  __shared__ int sids[128];
  const int tid = threadIdx.x;
  const int m0 = blockIdx.y * 128, n0 = blockIdx.x * 128;
  if (tid < 128) sids[tid] = ids[m0 + tid];
  const int wave = tid >> 6, lane = tid & 63, quad = lane >> 4, l15 = lane & 15;
  const int wm = wave >> 1, wn = wave & 1;

  floatx4 acc[4][4];
  for (int a = 0; a < 4; ++a)
    for (int b = 0; b < 4; ++b) acc[a][b] = (floatx4){0.f, 0.f, 0.f, 0.f};

  for (int kc = 0; kc < 32; ++kc) {
    __syncthreads();
    {  // stage A: 128 rows x 32 k (gather + fp32->fp16)
      const int row = tid >> 1, kh = tid & 1;
      const float4* s4 =
          (const float4*)(emb + (size_t)sids[row] * H + kc * 32 + kh * 16);
      float4 f0 = s4[0], f1 = s4[1], f2 = s4[2], f3 = s4[3];
      half8 p0 = {(_Float16)f0.x, (_Float16)f0.y, (_Float16)f0.z, (_Float16)f0.w,
                  (_Float16)f1.x, (_Float16)f1.y, (_Float16)f1.z, (_Float16)f1.w};
      half8 p1 = {(_Float16)f2.x, (_Float16)f2.y, (_Float16)f2.z, (_Float16)f2.w,
                  (_Float16)f3.x, (_Float16)f3.y, (_Float16)f3.z, (_Float16)f3.w};
      *(half8*)&As[row * 40 + kh * 16] = p0;
      *(half8*)&As[row * 40 + kh * 16 + 8] = p1;
    }
    for (int i = tid; i < 512; i += 256) {  // stage B: 128 n-rows x 32 k
      const int row = i >> 2, ko = (i & 3) * 8;
      *(half8*)&Bs[row * 40 + ko] =
          *(const half8*)(wihT + (size_t)(n0 + row) * H + kc * 32 + ko);
    }
    __syncthreads();
    half8 a[4], b[4];
    for (int tm = 0; tm < 4; ++tm)
      a[tm] = *(half8*)&As[(wm * 64 + tm * 16 + l15) * 40 + quad * 8];
    for (int tn = 0; tn < 4; ++tn)
      b[tn] = *(half8*)&Bs[(wn * 64 + tn * 16 + l15) * 40 + quad * 8];
    for (int tm = 0; tm < 4; ++tm)
      for (int tn = 0; tn < 4; ++tn)
        acc[tm][tn] =
            __builtin_amdgcn_mfma_f32_16x16x32_f16(a[tm], b[tn], acc[tm][tn], 0, 0, 0);
  }
  float bi[4];
  for (int tn = 0; tn < 4; ++tn) bi[tn] = bih[n0 + wn * 64 + tn * 16 + l15];
  for (int tm = 0; tm < 4; ++tm)
    for (int i = 0; i < 4; ++i) {
      const int m = m0 + wm * 64 + tm * 16 + quad * 4 + i;
      _Float16* dst = gi16 + (size_t)m * NG + n0 + wn * 64 + l15;
      for (int tn = 0; tn < 4; ++tn)
        dst[tn * 16] = (_Float16)(acc[tm][tn][i] + bi[tn]);
    }
}

// ---------------- phase B: 512-step recurrence, 64 persistent WGs ----------
// WG b owns j in [16b, 16b+16). Wave w owns k-quarter [256w, 256w+256) and
// keeps its 48-col W_hh k-slice in REGISTERS (24 half8, step-invariant).
// Per step: each wave MFMAs its k-quarter for all 4 batch tiles x 3 gates,
// partials exchanged through LDS; wave w finalizes batch tile w (16 rows).
// Barrier: per-step 64-byte arrival line, byte store + ulong polls (no RMW).
__global__ __launch_bounds__(256, 1) void gru_seq(
    const _Float16* __restrict__ whhT, const _Float16* __restrict__ gi16,
    const float* __restrict__ bhh, _Float16* __restrict__ h16,
    float* __restrict__ h32, unsigned char* __restrict__ arr) {
  __shared__ float part[48 * 256];  // [ (mt*3+g)*4 + producer_wave ][ lane*4 ]
  const int tid = threadIdx.x;
  const int bid = blockIdx.x;
  const int j0 = bid * 16;
  const int wave = tid >> 6, lane = tid & 63, quad = lane >> 4, l15 = lane & 15;
  const int j = j0 + l15;
  const int kbase = wave * 256;

  // B-fragments: step-invariant, load once from global into registers.
  // mfma B layout: lane l -> n=l&15 (col j0+l15), k = quad*8 + e.
  half8 B[3][8];
#pragma unroll
  for (int g = 0; g < 3; ++g)
#pragma unroll
    for (int kc = 0; kc < 8; ++kc)
      B[g][kc] = *(const half8*)(whhT + (size_t)(g * H + j) * H + kbase + kc * 32 + quad * 8);

  const float bh0 = bhh[j], bh1 = bhh[H + j], bh2 = bhh[2 * H + j];
  // each lane finalizes h for (b = wave*16 + quad*4 + i, j), i=0..3
  const int bmine = wave * 16 + quad * 4;
  float hprev[4] = {0.f, 0.f, 0.f, 0.f};
  float g0p[4], g1p[4], g2p[4];
#pragma unroll
  for (int i = 0; i < 4; ++i) {  // prefetch gi for t=0
    const _Float16* gp = gi16 + (size_t)(bmine + i) * NG + j;
    g0p[i] = (float)gp[0]; g1p[i] = (float)gp[H]; g2p[i] = (float)gp[2 * H];
  }

  for (int t = 0; t < SEQ; ++t) {
    const _Float16* hc = h16 + (t & 1) * (BATCH * H);
    _Float16* hn = h16 + ((t + 1) & 1) * (BATCH * H);

    floatx4 acc[4][3];
#pragma unroll
    for (int mt = 0; mt < 4; ++mt)
#pragma unroll
      for (int g = 0; g < 3; ++g) acc[mt][g] = (floatx4){0.f, 0.f, 0.f, 0.f};

#pragma unroll
    for (int kc = 0; kc < 8; ++kc) {
      half8 a[4];
#pragma unroll
      for (int mt = 0; mt < 4; ++mt)
        a[mt] = *(const half8*)(hc + (size_t)(mt * 16 + l15) * H + kbase + kc * 32 + quad * 8);
#pragma unroll
      for (int mt = 0; mt < 4; ++mt)
#pragma unroll
        for (int g = 0; g < 3; ++g)
          acc[mt][g] = __builtin_amdgcn_mfma_f32_16x16x32_f16(a[mt], B[g][kc], acc[mt][g], 0, 0, 0);
    }

    // snapshot current gi, prefetch next step's gi (gi is static data)
    float gc0[4], gc1[4], gc2[4];
#pragma unroll
    for (int i = 0; i < 4; ++i) { gc0[i] = g0p[i]; gc1[i] = g1p[i]; gc2[i] = g2p[i]; }
    const int tn = (t + 1 < SEQ) ? t + 1 : t;
#pragma unroll
    for (int i = 0; i < 4; ++i) {
      const _Float16* gp = gi16 + (size_t)(tn * BATCH + bmine + i) * NG + j;
      g0p[i] = (float)gp[0]; g1p[i] = (float)gp[H]; g2p[i] = (float)gp[2 * H];
    }

    // cross-wave k-reduction through LDS: write partials for tiles we don't own
#pragma unroll
    for (int mt = 0; mt < 4; ++mt)
      if (mt != wave)
#pragma unroll
        for (int g = 0; g < 3; ++g)
          *(floatx4*)&part[(size_t)((mt * 3 + g) * 4 + wave) * 256 + lane * 4] = acc[mt][g];
    __syncthreads();
    floatx4 s[3];
#pragma unroll
    for (int g = 0; g < 3; ++g) s[g] = acc[wave][g];
#pragma unroll
    for (int p = 0; p < 4; ++p)
      if (p != wave)
#pragma unroll
        for (int g = 0; g < 3; ++g)
          s[g] += *(floatx4*)&part[(size_t)((wave * 3 + g) * 4 + p) * 256 + lane * 4];

    // gates for own (b, j): D layout row=quad*4+i, col=l15
#pragma unroll
    for (int i = 0; i < 4; ++i) {
      const int b = bmine + i;
      const float r = 1.f / (1.f + __expf(-(gc0[i] + bh0 + s[0][i])));
      const float z = 1.f / (1.f + __expf(-(gc1[i] + bh1 + s[1][i])));
      const float pre = gc2[i] + r * (s[2][i] + bh2);
      const float e = __expf(2.f * pre);
      const float n = 1.f - 2.f / (e + 1.f);
      const float hv = (1.f - z) * n + z * hprev[i];
      hprev[i] = hv;
      hn[(size_t)b * H + j] = (_Float16)hv;
      if (t == SEQ - 1) h32[(size_t)b * H + j] = hv;
    }

    if (t < SEQ - 1) {
      __threadfence();     // release: h stores visible device-wide
      __syncthreads();     // whole WG drained
      if (tid == 0) {
        __hip_atomic_store(&arr[(size_t)t * 64 + bid], (unsigned char)1,
                           __ATOMIC_RELAXED, __HIP_MEMORY_SCOPE_AGENT);
        const unsigned long long* pl = (const unsigned long long*)(arr + (size_t)t * 64);
        for (;;) {
          unsigned long long v = ~0ull;
#pragma unroll
          for (int i = 0; i < 8; ++i)
            v &= __hip_atomic_load(pl + i, __ATOMIC_RELAXED, __HIP_MEMORY_SCOPE_AGENT);
          if (v == 0x0101010101010101ull) break;
          __builtin_amdgcn_s_sleep(2);
        }
      }
      __syncthreads();
      __threadfence();     // acquire: invalidate caches before reading new h
    }
  }
}

// ---------------- decode head: relu(h@W_dec+b_dec)@W_fc + b_fc ------------
__global__ __launch_bounds__(128) void decode_out(
    const float* __restrict__ h32, const float* __restrict__ Wdec,
    const float* __restrict__ bdec, const float* __restrict__ Wfc,
    const float* __restrict__ bfc, float* __restrict__ out) {
  __shared__ float dec[100];
  const int b = blockIdx.x, t = threadIdx.x;
  const float* h = h32 + b * H;
  if (t < 100) {
    float a = bdec[t];
    for (int k = 0; k < H; ++k) a += h[k] * Wdec[k * 100 + t];
    dec[t] = a > 0.f ? a : 0.f;
  }
  __syncthreads();
  if (t < 2) {
    float o = bfc[t];
    for (int d = 0; d < 100; ++d) o += dec[d] * Wfc[d * 2 + t];
    out[b * 2 + t] = o;
  }
}

// ---------------- launch ---------------------------------------------------
extern "C" void kernel_launch(void* const* d_in, const int* in_sizes, int n_in,
                              void* d_out, int out_size, void* d_ws, size_t ws_size,
                              hipStream_t stream) {
  const int* ids = (const int*)d_in[0];
  const float* emb = (const float*)d_in[1];
  const float* Wih = (const float*)d_in[2];
  const float* Whh = (const float*)d_in[3];
  const float* bih = (const float*)d_in[4];
  const float* bhh = (const float*)d_in[5];
  const float* Wdec = (const float*)d_in[6];
  const float* bdec = (const float*)d_in[7];
  const float* Wfc = (const float*)d_in[8];
  const float* bfc = (const float*)d_in[9];
  float* out = (float*)d_out;

  char* ws = (char*)d_ws;
  _Float16* gi16 = (_Float16*)(ws + OFF_GI);
  _Float16* wihT = (_Float16*)(ws + OFF_WIHT);
  _Float16* whhT = (_Float16*)(ws + OFF_WHHT);
  _Float16* h16 = (_Float16*)(ws + OFF_H16);
  float* h32 = (float*)(ws + OFF_H32);
  unsigned char* arr = (unsigned char*)(ws + OFF_ARR);

  // zero-init: h ping buffer (h0 = 0) and arrival flags (ws poisoned 0xAA)
  hipMemsetAsync(h16, 0, (size_t)BATCH * H * 2, stream);
  hipMemsetAsync(arr, 0, (size_t)SEQ * 64, stream);

  transpose_w<<<dim3(NG / 32, H / 32, 2), 256, 0, stream>>>(Wih, Whh, wihT, whhT);
  gemm_gi<<<dim3(NG / 128, (SEQ * BATCH) / 128), 256, 0, stream>>>(ids, emb, wihT,
                                                                   bih, gi16);
  gru_seq<<<64, 256, 0, stream>>>(whhT, gi16, bhh, h16, h32, arr);
  decode_out<<<BATCH, 128, 0, stream>>>(h32, Wdec, bdec, Wfc, bfc, out);
}

// Round 3
// 6729.181 us; speedup vs baseline: 3.4656x; 1.7078x over previous
//
#include <hip/hip_runtime.h>
#include <hip/hip_bf16.h>

// GRU model: emb gather -> gi = enc@W_ih+b_ih (fp16 MFMA GEMM)
//            -> 512-step recurrence (64 persistent WGs, fence-free flag barrier)
//            -> decode head.
// H=1024, SEQ=512, BATCH=64, VOCAB=32000. Output: [64,2] fp32.

typedef _Float16 half8 __attribute__((ext_vector_type(8)));
typedef float floatx4 __attribute__((ext_vector_type(4)));

#define H 1024
#define SEQ 512
#define BATCH 64
#define NG 3072  // 3*H

// ---------------- workspace layout (bytes) ----------------
static constexpr size_t OFF_GI   = 0;                                   // SEQ*BATCH*NG fp16
static constexpr size_t OFF_WIHT = OFF_GI + (size_t)SEQ * BATCH * NG * 2;
static constexpr size_t OFF_WHHT = OFF_WIHT + (size_t)NG * H * 2;
static constexpr size_t OFF_H16  = OFF_WHHT + (size_t)NG * H * 2;       // 2 x BATCH*H fp16 ping-pong
static constexpr size_t OFF_H32  = OFF_H16 + (size_t)2 * BATCH * H * 2; // BATCH*H fp32
static constexpr size_t OFF_FLG  = OFF_H32 + (size_t)BATCH * H * 4;     // SEQ*64 int arrival flags

__device__ __forceinline__ unsigned long long llc_load64(const void* p) {
  return __hip_atomic_load((const unsigned long long*)p, __ATOMIC_RELAXED,
                           __HIP_MEMORY_SCOPE_AGENT);
}
__device__ __forceinline__ void llc_store64(void* p, unsigned long long v) {
  __hip_atomic_store((unsigned long long*)p, v, __ATOMIC_RELAXED,
                     __HIP_MEMORY_SCOPE_AGENT);
}

// ---------------- prep: transpose+convert W (fp32 [H][3H] -> fp16 [3H][H]) --
__global__ __launch_bounds__(256) void transpose_w(
    const float* __restrict__ Wih, const float* __restrict__ Whh,
    _Float16* __restrict__ wihT, _Float16* __restrict__ whhT) {
  __shared__ float tile[32][33];
  const float* src = blockIdx.z ? Whh : Wih;
  _Float16* dst = blockIdx.z ? whhT : wihT;
  const int n0 = blockIdx.x * 32, k0 = blockIdx.y * 32;
  const int tx = threadIdx.x & 31, ty = threadIdx.x >> 5;  // ty in [0,8)
  for (int r = 0; r < 4; ++r)
    tile[r * 8 + ty][tx] = src[(size_t)(k0 + r * 8 + ty) * NG + n0 + tx];
  __syncthreads();
  for (int r = 0; r < 4; ++r)
    dst[(size_t)(n0 + r * 8 + ty) * H + k0 + tx] = (_Float16)tile[tx][r * 8 + ty];
}

// ---------------- phase A: gi16[m][c] = emb[ids[m]] @ W_ih + b_ih ----------
// 128x128 tile per WG, 4 waves each 64x64, mfma 16x16x32 f16.
__global__ __launch_bounds__(256) void gemm_gi(
    const int* __restrict__ ids, const float* __restrict__ emb,
    const _Float16* __restrict__ wihT, const float* __restrict__ bih,
    _Float16* __restrict__ gi16) {
  __shared__ _Float16 As[128 * 40];
  __shared__ _Float16 Bs[128 * 40];
  __shared__ int sids[128];
  const int tid = threadIdx.x;
  const int m0 = blockIdx.y * 128, n0 = blockIdx.x * 128;
  if (tid < 128) sids[tid] = ids[m0 + tid];
  const int wave = tid >> 6, lane = tid & 63, quad = lane >> 4, l15 = lane & 15;
  const int wm = wave >> 1, wn = wave & 1;

  floatx4 acc[4][4];
  for (int a = 0; a < 4; ++a)
    for (int b = 0; b < 4; ++b) acc[a][b] = (floatx4){0.f, 0.f, 0.f, 0.f};

  for (int kc = 0; kc < 32; ++kc) {
    __syncthreads();
    {  // stage A: 128 rows x 32 k (gather + fp32->fp16)
      const int row = tid >> 1, kh = tid & 1;
      const float4* s4 =
          (const float4*)(emb + (size_t)sids[row] * H + kc * 32 + kh * 16);
      float4 f0 = s4[0], f1 = s4[1], f2 = s4[2], f3 = s4[3];
      half8 p0 = {(_Float16)f0.x, (_Float16)f0.y, (_Float16)f0.z, (_Float16)f0.w,
                  (_Float16)f1.x, (_Float16)f1.y, (_Float16)f1.z, (_Float16)f1.w};
      half8 p1 = {(_Float16)f2.x, (_Float16)f2.y, (_Float16)f2.z, (_Float16)f2.w,
                  (_Float16)f3.x, (_Float16)f3.y, (_Float16)f3.z, (_Float16)f3.w};
      *(half8*)&As[row * 40 + kh * 16] = p0;
      *(half8*)&As[row * 40 + kh * 16 + 8] = p1;
    }
    for (int i = tid; i < 512; i += 256) {  // stage B: 128 n-rows x 32 k
      const int row = i >> 2, ko = (i & 3) * 8;
      *(half8*)&Bs[row * 40 + ko] =
          *(const half8*)(wihT + (size_t)(n0 + row) * H + kc * 32 + ko);
    }
    __syncthreads();
    half8 a[4], b[4];
    for (int tm = 0; tm < 4; ++tm)
      a[tm] = *(half8*)&As[(wm * 64 + tm * 16 + l15) * 40 + quad * 8];
    for (int tn = 0; tn < 4; ++tn)
      b[tn] = *(half8*)&Bs[(wn * 64 + tn * 16 + l15) * 40 + quad * 8];
    for (int tm = 0; tm < 4; ++tm)
      for (int tn = 0; tn < 4; ++tn)
        acc[tm][tn] =
            __builtin_amdgcn_mfma_f32_16x16x32_f16(a[tm], b[tn], acc[tm][tn], 0, 0, 0);
  }
  float bi[4];
  for (int tn = 0; tn < 4; ++tn) bi[tn] = bih[n0 + wn * 64 + tn * 16 + l15];
  for (int tm = 0; tm < 4; ++tm)
    for (int i = 0; i < 4; ++i) {
      const int m = m0 + wm * 64 + tm * 16 + quad * 4 + i;
      _Float16* dst = gi16 + (size_t)m * NG + n0 + wn * 64 + l15;
      for (int tn = 0; tn < 4; ++tn)
        dst[tn * 16] = (_Float16)(acc[tm][tn][i] + bi[tn]);
    }
}

// ---------------- phase B: 512-step recurrence, 64 persistent WGs ----------
// WG b owns j in [16b, 16b+16). Wave w owns k-quarter, W_hh slice in registers.
// Cross-WG h exchange: write-through 8B agent-scope atomic stores (no dirty
// L2 => no wbl2), per-wave s_waitcnt vmcnt(0) before arrive; dword flag per
// WG, tid0 polls with pipelined 8B atomic loads (pure reads, no RMW); one
// agent acquire fence (buffer_inv) per step, then normal cached b128 h loads.
__global__ __launch_bounds__(256, 1) void gru_seq(
    const _Float16* __restrict__ whhT, const _Float16* __restrict__ gi16,
    const float* __restrict__ bhh, _Float16* __restrict__ h16,
    float* __restrict__ h32, int* __restrict__ flags) {
  __shared__ float part[48 * 256];   // [ (mt*3+g)*4 + producer_wave ][ lane*4 ]
  __shared__ _Float16 hs[64 * 16];   // [b][jj] staging for coalesced h stores
  const int tid = threadIdx.x;
  const int bid = blockIdx.x;
  const int j0 = bid * 16;
  const int wave = tid >> 6, lane = tid & 63, quad = lane >> 4, l15 = lane & 15;
  const int j = j0 + l15;
  const int kbase = wave * 256;

  // B-fragments: step-invariant, load once from global into registers.
  half8 B[3][8];
#pragma unroll
  for (int g = 0; g < 3; ++g)
#pragma unroll
    for (int kc = 0; kc < 8; ++kc)
      B[g][kc] = *(const half8*)(whhT + (size_t)(g * H + j) * H + kbase + kc * 32 + quad * 8);

  const float bh0 = bhh[j], bh1 = bhh[H + j], bh2 = bhh[2 * H + j];
  const int bmine = wave * 16 + quad * 4;  // lane finalizes (bmine+i, j)
  float hprev[4] = {0.f, 0.f, 0.f, 0.f};
  float g0p[4], g1p[4], g2p[4];
#pragma unroll
  for (int i = 0; i < 4; ++i) {  // prefetch gi for t=0
    const _Float16* gp = gi16 + (size_t)(bmine + i) * NG + j;
    g0p[i] = (float)gp[0]; g1p[i] = (float)gp[H]; g2p[i] = (float)gp[2 * H];
  }

  for (int t = 0; t < SEQ; ++t) {
    const _Float16* hc = h16 + (t & 1) * (BATCH * H);
    _Float16* hn = h16 + ((t + 1) & 1) * (BATCH * H);

    floatx4 acc[4][3];
#pragma unroll
    for (int mt = 0; mt < 4; ++mt)
#pragma unroll
      for (int g = 0; g < 3; ++g) acc[mt][g] = (floatx4){0.f, 0.f, 0.f, 0.f};

#pragma unroll
    for (int kc = 0; kc < 8; ++kc) {
      half8 a[4];
#pragma unroll
      for (int mt = 0; mt < 4; ++mt)
        a[mt] = *(const half8*)(hc + (size_t)(mt * 16 + l15) * H + kbase + kc * 32 + quad * 8);
#pragma unroll
      for (int mt = 0; mt < 4; ++mt)
#pragma unroll
        for (int g = 0; g < 3; ++g)
          acc[mt][g] = __builtin_amdgcn_mfma_f32_16x16x32_f16(a[mt], B[g][kc], acc[mt][g], 0, 0, 0);
    }

    // snapshot current gi, prefetch next step's gi (gi is static data)
    float gc0[4], gc1[4], gc2[4];
#pragma unroll
    for (int i = 0; i < 4; ++i) { gc0[i] = g0p[i]; gc1[i] = g1p[i]; gc2[i] = g2p[i]; }
    const int tnx = (t + 1 < SEQ) ? t + 1 : t;
#pragma unroll
    for (int i = 0; i < 4; ++i) {
      const _Float16* gp = gi16 + (size_t)(tnx * BATCH + bmine + i) * NG + j;
      g0p[i] = (float)gp[0]; g1p[i] = (float)gp[H]; g2p[i] = (float)gp[2 * H];
    }

    // cross-wave k-reduction through LDS
#pragma unroll
    for (int mt = 0; mt < 4; ++mt)
      if (mt != wave)
#pragma unroll
        for (int g = 0; g < 3; ++g)
          *(floatx4*)&part[(size_t)((mt * 3 + g) * 4 + wave) * 256 + lane * 4] = acc[mt][g];
    __syncthreads();
    floatx4 s[3];
#pragma unroll
    for (int g = 0; g < 3; ++g) s[g] = acc[wave][g];
#pragma unroll
    for (int p = 0; p < 4; ++p)
      if (p != wave)
#pragma unroll
        for (int g = 0; g < 3; ++g)
          s[g] += *(floatx4*)&part[(size_t)((wave * 3 + g) * 4 + p) * 256 + lane * 4];

    // gates for own (b, j): D layout row=quad*4+i, col=l15
    float hv4[4];
#pragma unroll
    for (int i = 0; i < 4; ++i) {
      const float r = 1.f / (1.f + __expf(-(gc0[i] + bh0 + s[0][i])));
      const float z = 1.f / (1.f + __expf(-(gc1[i] + bh1 + s[1][i])));
      const float pre = gc2[i] + r * (s[2][i] + bh2);
      const float e = __expf(2.f * pre);
      const float n = 1.f - 2.f / (e + 1.f);
      const float hv = (1.f - z) * n + z * hprev[i];
      hprev[i] = hv;
      hv4[i] = hv;
    }

    if (t == SEQ - 1) {  // final: fp32 h out, no barrier needed
#pragma unroll
      for (int i = 0; i < 4; ++i) h32[(size_t)(bmine + i) * H + j] = hv4[i];
      break;
    }

    // stage new h slice in LDS, then write-through coalesced 8B atomic stores
#pragma unroll
    for (int i = 0; i < 4; ++i) hs[(bmine + i) * 16 + l15] = (_Float16)hv4[i];
    __syncthreads();
    {
      const int b = tid >> 2, seg = tid & 3;
      const unsigned long long v = *(const unsigned long long*)&hs[b * 16 + seg * 4];
      llc_store64((char*)hn + ((size_t)b * H + j0 + seg * 4) * 2, v);
    }
    asm volatile("s_waitcnt vmcnt(0)" ::: "memory");  // stores acked at LLC
    __syncthreads();
    if (tid == 0) {
      __hip_atomic_store(&flags[t * 64 + bid], 1, __ATOMIC_RELAXED,
                         __HIP_MEMORY_SCOPE_AGENT);
      const char* pl = (const char*)(flags + t * 64);
      for (;;) {
        unsigned long long v = ~0ull;
#pragma unroll
        for (int i = 0; i < 32; ++i) v &= llc_load64(pl + i * 8);
        if (v == 0x0000000100000001ull) break;
      }
    }
    __syncthreads();
    __builtin_amdgcn_fence(__ATOMIC_ACQUIRE, "agent");  // buffer_inv: see fresh h
  }
}

// ---------------- decode head: relu(h@W_dec+b_dec)@W_fc + b_fc ------------
__global__ __launch_bounds__(128) void decode_out(
    const float* __restrict__ h32, const float* __restrict__ Wdec,
    const float* __restrict__ bdec, const float* __restrict__ Wfc,
    const float* __restrict__ bfc, float* __restrict__ out) {
  __shared__ float dec[100];
  const int b = blockIdx.x, t = threadIdx.x;
  const float* h = h32 + b * H;
  if (t < 100) {
    float a = bdec[t];
    for (int k = 0; k < H; ++k) a += h[k] * Wdec[k * 100 + t];
    dec[t] = a > 0.f ? a : 0.f;
  }
  __syncthreads();
  if (t < 2) {
    float o = bfc[t];
    for (int d = 0; d < 100; ++d) o += dec[d] * Wfc[d * 2 + t];
    out[b * 2 + t] = o;
  }
}

// ---------------- launch ---------------------------------------------------
extern "C" void kernel_launch(void* const* d_in, const int* in_sizes, int n_in,
                              void* d_out, int out_size, void* d_ws, size_t ws_size,
                              hipStream_t stream) {
  const int* ids = (const int*)d_in[0];
  const float* emb = (const float*)d_in[1];
  const float* Wih = (const float*)d_in[2];
  const float* Whh = (const float*)d_in[3];
  const float* bih = (const float*)d_in[4];
  const float* bhh = (const float*)d_in[5];
  const float* Wdec = (const float*)d_in[6];
  const float* bdec = (const float*)d_in[7];
  const float* Wfc = (const float*)d_in[8];
  const float* bfc = (const float*)d_in[9];
  float* out = (float*)d_out;

  char* ws = (char*)d_ws;
  _Float16* gi16 = (_Float16*)(ws + OFF_GI);
  _Float16* wihT = (_Float16*)(ws + OFF_WIHT);
  _Float16* whhT = (_Float16*)(ws + OFF_WHHT);
  _Float16* h16 = (_Float16*)(ws + OFF_H16);
  float* h32 = (float*)(ws + OFF_H32);
  int* flags = (int*)(ws + OFF_FLG);

  // zero-init: h ping buffer (h0 = 0) and arrival flags (ws poisoned 0xAA)
  hipMemsetAsync(h16, 0, (size_t)BATCH * H * 2, stream);
  hipMemsetAsync(flags, 0, (size_t)SEQ * 64 * 4, stream);

  transpose_w<<<dim3(NG / 32, H / 32, 2), 256, 0, stream>>>(Wih, Whh, wihT, whhT);
  gemm_gi<<<dim3(NG / 128, (SEQ * BATCH) / 128), 256, 0, stream>>>(ids, emb, wihT,
                                                                   bih, gi16);
  gru_seq<<<64, 256, 0, stream>>>(whhT, gi16, bhh, h16, h32, flags);
  decode_out<<<BATCH, 128, 0, stream>>>(h32, Wdec, bdec, Wfc, bfc, out);
}

// Round 4
// 6051.381 us; speedup vs baseline: 3.8537x; 1.1120x over previous
//
#include <hip/hip_runtime.h>
#include <hip/hip_bf16.h>

// GRU model: emb gather -> gi = enc@W_ih+b_ih (fp16 MFMA GEMM)
//            -> 512-step recurrence (64 persistent WGs, single-poller barrier)
//            -> decode head.
// H=1024, SEQ=512, BATCH=64, VOCAB=32000. Output: [64,2] fp32.

typedef _Float16 half8 __attribute__((ext_vector_type(8)));
typedef float floatx4 __attribute__((ext_vector_type(4)));

#define H 1024
#define SEQ 512
#define BATCH 64
#define NG 3072  // 3*H

// ---------------- workspace layout (bytes) ----------------
static constexpr size_t OFF_GI   = 0;                                   // SEQ*BATCH*NG fp16
static constexpr size_t OFF_WIHT = OFF_GI + (size_t)SEQ * BATCH * NG * 2;
static constexpr size_t OFF_WHHT = OFF_WIHT + (size_t)NG * H * 2;
static constexpr size_t OFF_H16  = OFF_WHHT + (size_t)NG * H * 2;       // 2 x BATCH*H fp16 ping-pong
static constexpr size_t OFF_H32  = OFF_H16 + (size_t)2 * BATCH * H * 2; // BATCH*H fp32
static constexpr size_t OFF_FLG  = OFF_H32 + (size_t)BATCH * H * 4;     // SEQ x 64 int arrive flags
static constexpr size_t OFF_REL  = OFF_FLG + (size_t)SEQ * 64 * 4;      // SEQ x 32-int-stride release

__device__ __forceinline__ unsigned long long llc_load64(const void* p) {
  return __hip_atomic_load((const unsigned long long*)p, __ATOMIC_RELAXED,
                           __HIP_MEMORY_SCOPE_AGENT);
}
__device__ __forceinline__ void llc_store64(void* p, unsigned long long v) {
  __hip_atomic_store((unsigned long long*)p, v, __ATOMIC_RELAXED,
                     __HIP_MEMORY_SCOPE_AGENT);
}

// ---------------- prep: transpose+convert W (fp32 [H][3H] -> fp16 [3H][H]) --
__global__ __launch_bounds__(256) void transpose_w(
    const float* __restrict__ Wih, const float* __restrict__ Whh,
    _Float16* __restrict__ wihT, _Float16* __restrict__ whhT) {
  __shared__ float tile[32][33];
  const float* src = blockIdx.z ? Whh : Wih;
  _Float16* dst = blockIdx.z ? whhT : wihT;
  const int n0 = blockIdx.x * 32, k0 = blockIdx.y * 32;
  const int tx = threadIdx.x & 31, ty = threadIdx.x >> 5;  // ty in [0,8)
  for (int r = 0; r < 4; ++r)
    tile[r * 8 + ty][tx] = src[(size_t)(k0 + r * 8 + ty) * NG + n0 + tx];
  __syncthreads();
  for (int r = 0; r < 4; ++r)
    dst[(size_t)(n0 + r * 8 + ty) * H + k0 + tx] = (_Float16)tile[tx][r * 8 + ty];
}

// ---------------- phase A: gi16[m][c] = emb[ids[m]] @ W_ih + b_ih ----------
// 128x128 tile per WG, 4 waves each 64x64, mfma 16x16x32 f16.
__global__ __launch_bounds__(256) void gemm_gi(
    const int* __restrict__ ids, const float* __restrict__ emb,
    const _Float16* __restrict__ wihT, const float* __restrict__ bih,
    _Float16* __restrict__ gi16) {
  __shared__ _Float16 As[128 * 40];
  __shared__ _Float16 Bs[128 * 40];
  __shared__ int sids[128];
  const int tid = threadIdx.x;
  const int m0 = blockIdx.y * 128, n0 = blockIdx.x * 128;
  if (tid < 128) sids[tid] = ids[m0 + tid];
  const int wave = tid >> 6, lane = tid & 63, quad = lane >> 4, l15 = lane & 15;
  const int wm = wave >> 1, wn = wave & 1;

  floatx4 acc[4][4];
  for (int a = 0; a < 4; ++a)
    for (int b = 0; b < 4; ++b) acc[a][b] = (floatx4){0.f, 0.f, 0.f, 0.f};

  for (int kc = 0; kc < 32; ++kc) {
    __syncthreads();
    {  // stage A: 128 rows x 32 k (gather + fp32->fp16)
      const int row = tid >> 1, kh = tid & 1;
      const float4* s4 =
          (const float4*)(emb + (size_t)sids[row] * H + kc * 32 + kh * 16);
      float4 f0 = s4[0], f1 = s4[1], f2 = s4[2], f3 = s4[3];
      half8 p0 = {(_Float16)f0.x, (_Float16)f0.y, (_Float16)f0.z, (_Float16)f0.w,
                  (_Float16)f1.x, (_Float16)f1.y, (_Float16)f1.z, (_Float16)f1.w};
      half8 p1 = {(_Float16)f2.x, (_Float16)f2.y, (_Float16)f2.z, (_Float16)f2.w,
                  (_Float16)f3.x, (_Float16)f3.y, (_Float16)f3.z, (_Float16)f3.w};
      *(half8*)&As[row * 40 + kh * 16] = p0;
      *(half8*)&As[row * 40 + kh * 16 + 8] = p1;
    }
    for (int i = tid; i < 512; i += 256) {  // stage B: 128 n-rows x 32 k
      const int row = i >> 2, ko = (i & 3) * 8;
      *(half8*)&Bs[row * 40 + ko] =
          *(const half8*)(wihT + (size_t)(n0 + row) * H + kc * 32 + ko);
    }
    __syncthreads();
    half8 a[4], b[4];
    for (int tm = 0; tm < 4; ++tm)
      a[tm] = *(half8*)&As[(wm * 64 + tm * 16 + l15) * 40 + quad * 8];
    for (int tn = 0; tn < 4; ++tn)
      b[tn] = *(half8*)&Bs[(wn * 64 + tn * 16 + l15) * 40 + quad * 8];
    for (int tm = 0; tm < 4; ++tm)
      for (int tn = 0; tn < 4; ++tn)
        acc[tm][tn] =
            __builtin_amdgcn_mfma_f32_16x16x32_f16(a[tm], b[tn], acc[tm][tn], 0, 0, 0);
  }
  float bi[4];
  for (int tn = 0; tn < 4; ++tn) bi[tn] = bih[n0 + wn * 64 + tn * 16 + l15];
  for (int tm = 0; tm < 4; ++tm)
    for (int i = 0; i < 4; ++i) {
      const int m = m0 + wm * 64 + tm * 16 + quad * 4 + i;
      _Float16* dst = gi16 + (size_t)m * NG + n0 + wn * 64 + l15;
      for (int tn = 0; tn < 4; ++tn)
        dst[tn * 16] = (_Float16)(acc[tm][tn][i] + bi[tn]);
    }
}

// ---------------- phase B: 512-step recurrence, 64 persistent WGs ----------
// WG b owns j in [16b, 16b+16). Wave w owns k-quarter, W_hh slice in registers.
// h exchange: write-through 8B agent atomic stores + vmcnt(0) ack.
// Barrier: arrive flags (one int/WG, per-step line); ONLY WG0 polls them
// (sole heavy poller -> no LLC flood), then stores a release word; other WGs
// poll the single release word (1 load per RT each). One agent acquire fence
// (buffer_inv) per step, then normal cached b128 h loads.
__global__ __launch_bounds__(256, 1) void gru_seq(
    const _Float16* __restrict__ whhT, const _Float16* __restrict__ gi16,
    const float* __restrict__ bhh, _Float16* __restrict__ h16,
    float* __restrict__ h32, int* __restrict__ flags, int* __restrict__ rel) {
  __shared__ float part[48 * 256];   // [ (mt*3+g)*4 + producer_wave ][ lane*4 ]
  __shared__ _Float16 hs[64 * 16];   // [b][jj] staging for coalesced h stores
  const int tid = threadIdx.x;
  const int bid = blockIdx.x;
  const int j0 = bid * 16;
  const int wave = tid >> 6, lane = tid & 63, quad = lane >> 4, l15 = lane & 15;
  const int j = j0 + l15;
  const int kbase = wave * 256;

  // B-fragments: step-invariant, load once from global into registers.
  half8 B[3][8];
#pragma unroll
  for (int g = 0; g < 3; ++g)
#pragma unroll
    for (int kc = 0; kc < 8; ++kc)
      B[g][kc] = *(const half8*)(whhT + (size_t)(g * H + j) * H + kbase + kc * 32 + quad * 8);

  const float bh0 = bhh[j], bh1 = bhh[H + j], bh2 = bhh[2 * H + j];
  const int bmine = wave * 16 + quad * 4;  // lane finalizes (bmine+i, j)
  float hprev[4] = {0.f, 0.f, 0.f, 0.f};
  float g0p[4], g1p[4], g2p[4];
#pragma unroll
  for (int i = 0; i < 4; ++i) {  // prefetch gi for t=0
    const _Float16* gp = gi16 + (size_t)(bmine + i) * NG + j;
    g0p[i] = (float)gp[0]; g1p[i] = (float)gp[H]; g2p[i] = (float)gp[2 * H];
  }

  for (int t = 0; t < SEQ; ++t) {
    const _Float16* hc = h16 + (t & 1) * (BATCH * H);
    _Float16* hn = h16 + ((t + 1) & 1) * (BATCH * H);

    // snapshot current gi, then immediately issue next step's prefetch so it
    // completes long before the pre-arrive vmcnt(0).
    float gc0[4], gc1[4], gc2[4];
#pragma unroll
    for (int i = 0; i < 4; ++i) { gc0[i] = g0p[i]; gc1[i] = g1p[i]; gc2[i] = g2p[i]; }
    const int tnx = (t + 1 < SEQ) ? t + 1 : t;
#pragma unroll
    for (int i = 0; i < 4; ++i) {
      const _Float16* gp = gi16 + (size_t)(tnx * BATCH + bmine + i) * NG + j;
      g0p[i] = (float)gp[0]; g1p[i] = (float)gp[H]; g2p[i] = (float)gp[2 * H];
    }

    floatx4 acc[4][3];
#pragma unroll
    for (int mt = 0; mt < 4; ++mt)
#pragma unroll
      for (int g = 0; g < 3; ++g) acc[mt][g] = (floatx4){0.f, 0.f, 0.f, 0.f};

#pragma unroll
    for (int kc = 0; kc < 8; ++kc) {
      half8 a[4];
#pragma unroll
      for (int mt = 0; mt < 4; ++mt)
        a[mt] = *(const half8*)(hc + (size_t)(mt * 16 + l15) * H + kbase + kc * 32 + quad * 8);
#pragma unroll
      for (int mt = 0; mt < 4; ++mt)
#pragma unroll
        for (int g = 0; g < 3; ++g)
          acc[mt][g] = __builtin_amdgcn_mfma_f32_16x16x32_f16(a[mt], B[g][kc], acc[mt][g], 0, 0, 0);
    }

    // cross-wave k-reduction through LDS
#pragma unroll
    for (int mt = 0; mt < 4; ++mt)
      if (mt != wave)
#pragma unroll
        for (int g = 0; g < 3; ++g)
          *(floatx4*)&part[(size_t)((mt * 3 + g) * 4 + wave) * 256 + lane * 4] = acc[mt][g];
    __syncthreads();
    floatx4 s[3];
#pragma unroll
    for (int g = 0; g < 3; ++g) s[g] = acc[wave][g];
#pragma unroll
    for (int p = 0; p < 4; ++p)
      if (p != wave)
#pragma unroll
        for (int g = 0; g < 3; ++g)
          s[g] += *(floatx4*)&part[(size_t)((wave * 3 + g) * 4 + p) * 256 + lane * 4];

    // gates for own (b, j): D layout row=quad*4+i, col=l15
    float hv4[4];
#pragma unroll
    for (int i = 0; i < 4; ++i) {
      const float r = 1.f / (1.f + __expf(-(gc0[i] + bh0 + s[0][i])));
      const float z = 1.f / (1.f + __expf(-(gc1[i] + bh1 + s[1][i])));
      const float pre = gc2[i] + r * (s[2][i] + bh2);
      const float e = __expf(2.f * pre);
      const float n = 1.f - 2.f / (e + 1.f);
      const float hv = (1.f - z) * n + z * hprev[i];
      hprev[i] = hv;
      hv4[i] = hv;
    }

    if (t == SEQ - 1) {  // final: fp32 h out, no barrier needed
#pragma unroll
      for (int i = 0; i < 4; ++i) h32[(size_t)(bmine + i) * H + j] = hv4[i];
      break;
    }

    // stage new h slice in LDS, then write-through coalesced 8B atomic stores
#pragma unroll
    for (int i = 0; i < 4; ++i) hs[(bmine + i) * 16 + l15] = (_Float16)hv4[i];
    __syncthreads();
    {
      const int b = tid >> 2, seg = tid & 3;
      const unsigned long long v = *(const unsigned long long*)&hs[b * 16 + seg * 4];
      llc_store64((char*)hn + ((size_t)b * H + j0 + seg * 4) * 2, v);
    }
    asm volatile("s_waitcnt vmcnt(0)" ::: "memory");  // h stores acked at LLC
    __syncthreads();
    if (tid == 0) {
      __hip_atomic_store(&flags[t * 64 + bid], 1, __ATOMIC_RELAXED,
                         __HIP_MEMORY_SCOPE_AGENT);
      if (bid == 0) {  // sole aggregator: poll 64 arrive flags
        const char* pl = (const char*)(flags + t * 64);
        for (;;) {
          unsigned long long v = ~0ull;
#pragma unroll
          for (int i = 0; i < 32; ++i) v &= llc_load64(pl + i * 8);
          if (v == 0x0000000100000001ull) break;
        }
        __hip_atomic_store(&rel[t * 32], 1, __ATOMIC_RELAXED,
                           __HIP_MEMORY_SCOPE_AGENT);
      } else {  // everyone else: poll the single release word
        while (__hip_atomic_load(&rel[t * 32], __ATOMIC_RELAXED,
                                 __HIP_MEMORY_SCOPE_AGENT) == 0) {
        }
      }
    }
    __syncthreads();
    __builtin_amdgcn_fence(__ATOMIC_ACQUIRE, "agent");  // buffer_inv: see fresh h
  }
}

// ---------------- decode head: relu(h@W_dec+b_dec)@W_fc + b_fc ------------
__global__ __launch_bounds__(128) void decode_out(
    const float* __restrict__ h32, const float* __restrict__ Wdec,
    const float* __restrict__ bdec, const float* __restrict__ Wfc,
    const float* __restrict__ bfc, float* __restrict__ out) {
  __shared__ float dec[100];
  const int b = blockIdx.x, t = threadIdx.x;
  const float* h = h32 + b * H;
  if (t < 100) {
    float a = bdec[t];
    for (int k = 0; k < H; ++k) a += h[k] * Wdec[k * 100 + t];
    dec[t] = a > 0.f ? a : 0.f;
  }
  __syncthreads();
  if (t < 2) {
    float o = bfc[t];
    for (int d = 0; d < 100; ++d) o += dec[d] * Wfc[d * 2 + t];
    out[b * 2 + t] = o;
  }
}

// ---------------- launch ---------------------------------------------------
extern "C" void kernel_launch(void* const* d_in, const int* in_sizes, int n_in,
                              void* d_out, int out_size, void* d_ws, size_t ws_size,
                              hipStream_t stream) {
  const int* ids = (const int*)d_in[0];
  const float* emb = (const float*)d_in[1];
  const float* Wih = (const float*)d_in[2];
  const float* Whh = (const float*)d_in[3];
  const float* bih = (const float*)d_in[4];
  const float* bhh = (const float*)d_in[5];
  const float* Wdec = (const float*)d_in[6];
  const float* bdec = (const float*)d_in[7];
  const float* Wfc = (const float*)d_in[8];
  const float* bfc = (const float*)d_in[9];
  float* out = (float*)d_out;

  char* ws = (char*)d_ws;
  _Float16* gi16 = (_Float16*)(ws + OFF_GI);
  _Float16* wihT = (_Float16*)(ws + OFF_WIHT);
  _Float16* whhT = (_Float16*)(ws + OFF_WHHT);
  _Float16* h16 = (_Float16*)(ws + OFF_H16);
  float* h32 = (float*)(ws + OFF_H32);
  int* flags = (int*)(ws + OFF_FLG);
  int* rel = (int*)(ws + OFF_REL);

  // zero-init: h ping buffer (h0 = 0) + arrive/release flags (ws poisoned 0xAA)
  hipMemsetAsync(h16, 0, (size_t)BATCH * H * 2, stream);
  hipMemsetAsync(flags, 0, (size_t)SEQ * 64 * 4 + (size_t)SEQ * 32 * 4, stream);

  transpose_w<<<dim3(NG / 32, H / 32, 2), 256, 0, stream>>>(Wih, Whh, wihT, whhT);
  gemm_gi<<<dim3(NG / 128, (SEQ * BATCH) / 128), 256, 0, stream>>>(ids, emb, wihT,
                                                                   bih, gi16);
  gru_seq<<<64, 256, 0, stream>>>(whhT, gi16, bhh, h16, h32, flags, rel);
  decode_out<<<BATCH, 128, 0, stream>>>(h32, Wdec, bdec, Wfc, bfc, out);
}